// Round 6
// baseline (167.736 us; speedup 1.0000x reference)
//
#include <hip/hip_runtime.h>
#include <hip/hip_bf16.h>

#define HID 768
#define ENTS 9
#define DD 64
#define NOUT 1152     // ENTS*2*DD
#define BATCH 16
#define SEQ 512
#define BIGF 1000000000000.0f
#define NCHUNK 16

typedef __attribute__((ext_vector_type(8))) short short8;
typedef __attribute__((ext_vector_type(4))) short short4_t;
typedef __attribute__((ext_vector_type(4))) float floatx4;
typedef __attribute__((ext_vector_type(2))) float floatx2;
typedef __attribute__((ext_vector_type(4))) int intx4;
typedef unsigned short ushort_t;

static __device__ __forceinline__ ushort_t f2bf(float x) {
    unsigned int u = __float_as_uint(x);
    unsigned int r = (u + 0x7FFFu + ((u >> 16) & 1u)) >> 16;   // RNE
    return (ushort_t)r;
}

static __device__ __forceinline__ void gload16(const void* g, void* l) {
    __builtin_amdgcn_global_load_lds(
        (const __attribute__((address_space(1))) void*)g,
        (__attribute__((address_space(3))) void*)l, 16, 0, 0);
}

// ---------------- RoPE tables: sin/cos (SEQ x 32) ----------------
__global__ void rope_table_kernel(float* __restrict__ sin_t, float* __restrict__ cos_t) {
    int idx = blockIdx.x * blockDim.x + threadIdx.x;   // 512*32 = 16384
    if (idx >= SEQ * 32) return;
    int m = idx >> 5, i = idx & 31;
    float inv = powf(10000.0f, -2.0f * (float)i / 64.0f);
    float ang = (float)m * inv;
    sin_t[idx] = sinf(ang);
    cos_t[idx] = cosf(ang);
}

// ---------------- f32 -> bf16 convert (X) ----------------
__global__ void cvt_x_kernel(const float* __restrict__ X, ushort_t* __restrict__ Xb, int n) {
    int i = (blockIdx.x * blockDim.x + threadIdx.x) * 4;
    int stride = gridDim.x * blockDim.x * 4;
    for (; i < n; i += stride) {
        float4 f = *(const float4*)&X[i];
        ushort_t u0 = f2bf(f.x), u1 = f2bf(f.y), u2 = f2bf(f.z), u3 = f2bf(f.w);
        ushort_t* p = &Xb[i];
        p[0] = u0; p[1] = u1; p[2] = u2; p[3] = u3;
    }
}

// ---------------- W transpose + convert: Wt[n][k] = bf16(W[k][n]) ----------------
__global__ void cvt_w_kernel(const float* __restrict__ W, ushort_t* __restrict__ Wt) {
    int idx = blockIdx.x * blockDim.x + threadIdx.x;   // over 1152*768
    if (idx >= NOUT * HID) return;
    int n = idx / HID, k = idx - n * HID;
    Wt[idx] = f2bf(W[(size_t)k * NOUT + n]);
}

// ---------------- Projection GEMM + bias + RoPE + pack to q/k bf16 ----------------
__global__ __launch_bounds__(256) void proj_rope_kernel(
    const ushort_t* __restrict__ Xb, const ushort_t* __restrict__ Wt,
    const float* __restrict__ bias,
    const float* __restrict__ sin_t, const float* __restrict__ cos_t,
    ushort_t* __restrict__ qbuf, ushort_t* __restrict__ kbuf)
{
    __shared__ ushort_t As[128 * 32];   // linear: global_load_lds dest
    __shared__ ushort_t Bs[128 * 32];
    const int tid  = threadIdx.x;
    const int lane = tid & 63;
    const int wave = tid >> 6;
    const int bm = blockIdx.x * 128;
    const int bn = blockIdx.y * 128;
    const int wm = (wave >> 1) * 64;
    const int wn = (wave & 1) * 64;

    floatx4 acc[4][4];
    #pragma unroll
    for (int j = 0; j < 4; ++j)
        #pragma unroll
        for (int i = 0; i < 4; ++i) { floatx4 z = {0.f,0.f,0.f,0.f}; acc[j][i] = z; }

    const int c0 = wave * 64 + lane;
    const int c1 = 256 + wave * 64 + lane;
    const int r0 = c0 >> 2, q0 = (c0 & 3) * 8;
    const int r1 = c1 >> 2, q1 = (c1 & 3) * 8;
    ushort_t* ldsA0 = As + wave * 512;
    ushort_t* ldsA1 = As + 2048 + wave * 512;
    ushort_t* ldsB0 = Bs + wave * 512;
    ushort_t* ldsB1 = Bs + 2048 + wave * 512;

    const int ko = (lane >> 4) * 8;
    const int lr = lane & 15;

    for (int kt = 0; kt < HID; kt += 32) {
        gload16(&Xb[(size_t)(bm + r0) * HID + kt + q0], ldsA0);
        gload16(&Xb[(size_t)(bm + r1) * HID + kt + q1], ldsA1);
        gload16(&Wt[(size_t)(bn + r0) * HID + kt + q0], ldsB0);
        gload16(&Wt[(size_t)(bn + r1) * HID + kt + q1], ldsB1);
        __syncthreads();

        short8 a[4], b[4];
        #pragma unroll
        for (int i = 0; i < 4; ++i) a[i] = *(const short8*)&As[(wm + i*16 + lr) * 32 + ko];
        #pragma unroll
        for (int j = 0; j < 4; ++j) b[j] = *(const short8*)&Bs[(wn + j*16 + lr) * 32 + ko];
        #pragma unroll
        for (int j = 0; j < 4; ++j)
            #pragma unroll
            for (int i = 0; i < 4; ++i)
                acc[j][i] = __builtin_amdgcn_mfma_f32_16x16x32_bf16(b[j], a[i], acc[j][i], 0, 0, 0);
        __syncthreads();
    }

    #pragma unroll
    for (int j = 0; j < 4; ++j) {
        const int n0 = bn + wn + j*16 + (lane >> 4) * 4;   // 4 consecutive n
        const int e   = n0 >> 7;
        const int dd0 = n0 & 127;
        const bool isq = dd0 < DD;
        const int d0  = isq ? dd0 : dd0 - DD;              // multiple of 4
        const float4 bv = *(const float4*)&bias[n0];
        #pragma unroll
        for (int i = 0; i < 4; ++i) {
            const int m = bm + wm + i*16 + lr;
            const int s  = m & (SEQ - 1);
            const int bb = m >> 9;
            const float c0f = cos_t[s*32 + (d0 >> 1)];
            const float s0f = sin_t[s*32 + (d0 >> 1)];
            const float c1f = cos_t[s*32 + (d0 >> 1) + 1];
            const float s1f = sin_t[s*32 + (d0 >> 1) + 1];
            const float v0 = acc[j][i][0] + bv.x;
            const float v1 = acc[j][i][1] + bv.y;
            const float v2 = acc[j][i][2] + bv.z;
            const float v3 = acc[j][i][3] + bv.w;
            const float o0 = v0 * c0f - v1 * s0f;
            const float o1 = v1 * c0f + v0 * s0f;
            const float o2 = v2 * c1f - v3 * s1f;
            const float o3 = v3 * c1f + v2 * s1f;
            short4_t sv = { (short)f2bf(o0), (short)f2bf(o1), (short)f2bf(o2), (short)f2bf(o3) };
            size_t oidx = (((size_t)(bb * ENTS + e) * SEQ) + s) * DD + d0;
            *(short4_t*)&(isq ? qbuf : kbuf)[oidx] = sv;
        }
    }
}

// ---------------- lse merge helper ----------------
static __device__ __forceinline__ void lse_merge(float& mx, float& sm, float mo, float so) {
    if (mo > mx) { sm = sm * __expf(mx - mo) + so; mx = mo; }
    else         { sm += so * __expf(mo - mx); }
}

// ---------------- Batched QK^T + masks + scale -> temp_logits, FUSED CE partials ----------------
// No LDS staging, no barriers: Q/K MFMA fragments are contiguous 16B runs of
// qbuf/kbuf rows -> loaded directly from global (L2-resident per bh slice).
// Labels fully prefetched at entry (nt) and genuinely overlap compute since
// no vmcnt(0)+barrier drain exists. Aligned full-line logit stores as R5.
__global__ __launch_bounds__(256) void qk_mask_ce_kernel(
    const ushort_t* __restrict__ qbuf, const ushort_t* __restrict__ kbuf,
    const int* __restrict__ amask, const int* __restrict__ labels,
    float* __restrict__ logits, float* __restrict__ partials)
{
    __shared__ float smx[2][4], ssm[2][4];
    const int tid  = threadIdx.x;
    const int lane = tid & 63;
    const int wave = tid >> 6;
    const int bm = blockIdx.x * 128;
    const int bn = blockIdx.y * 128;
    const int bh = blockIdx.z;           // b*ENTS + h
    const int b  = bh / ENTS;
    const int wm = (wave >> 1) * 64;
    const int wn = (wave & 1) * 64;
    const size_t base = (size_t)bh * SEQ * DD;

    const int g  = lane >> 4;
    const int lr = lane & 15;
    const int ko = g * 8;
    const int r0 = bm + wm + lr;                 // m base (i=0)
    const int W  = bn + wn;                      // wave n-column base (64-wide)
    const int n00 = W + (g << 2);
    const int bhbase = bh << 18;                 // bh*512*512 (fits int)

    // ---- prefetch ALL labels for this thread's 64 outputs (nt) ----
    intx4 y[4][4];
    #pragma unroll
    for (int j = 0; j < 4; ++j)
        #pragma unroll
        for (int i = 0; i < 4; ++i)
            y[j][i] = __builtin_nontemporal_load(
                (const intx4*)&labels[bhbase + ((r0 + i*16) << 9) + n00 + j*16]);

    intx4 p4[4];
    #pragma unroll
    for (int j = 0; j < 4; ++j)
        p4[j] = *(const intx4*)&amask[(b << 9) + n00 + j*16];

    // ---- Q fragments direct from global (row = wm+i*16+lr, 16B contiguous k-run) ----
    short8 a[2][4];
    #pragma unroll
    for (int kk = 0; kk < 2; ++kk)
        #pragma unroll
        for (int i = 0; i < 4; ++i)
            a[kk][i] = *(const short8*)&qbuf[base + (size_t)(r0 + i*16) * DD + kk*32 + ko];

    float mxn = -3.0e38f, smn = 0.f, mxp = -3.0e38f, smp = 0.f;
    float tl[4];                                  // per-row tail (valid on g==3 lanes)
    float* __restrict__ lgb = logits + bhbase;

    #pragma unroll
    for (int jp = 0; jp < 2; ++jp) {
        const int jA = jp * 2, jB = jp * 2 + 1;

        // --- K fragments direct from global, then MFMA for the pair ---
        short8 bfA[2], bfB[2];
        #pragma unroll
        for (int kk = 0; kk < 2; ++kk) {
            bfA[kk] = *(const short8*)&kbuf[base + (size_t)(bn + wn + jA*16 + lr) * DD + kk*32 + ko];
            bfB[kk] = *(const short8*)&kbuf[base + (size_t)(bn + wn + jB*16 + lr) * DD + kk*32 + ko];
        }
        floatx4 accA[4], accB[4];
        #pragma unroll
        for (int i = 0; i < 4; ++i) { floatx4 z = {0.f,0.f,0.f,0.f}; accA[i] = z; accB[i] = z; }
        #pragma unroll
        for (int kk = 0; kk < 2; ++kk) {
            #pragma unroll
            for (int i = 0; i < 4; ++i) {
                accA[i] = __builtin_amdgcn_mfma_f32_16x16x32_bf16(bfA[kk], a[kk][i], accA[i], 0, 0, 0);
                accB[i] = __builtin_amdgcn_mfma_f32_16x16x32_bf16(bfB[kk], a[kk][i], accB[i], 0, 0, 0);
            }
        }

        // --- pass A: mask + scale + CE maxes + label bits (32 values) ---
        unsigned int yb = 0;
        float mxnj = -3.0e38f, mxpj = -3.0e38f;
        int cnt = 0;
        #pragma unroll
        for (int half = 0; half < 2; ++half) {
            const int j = half ? jB : jA;
            const intx4 pm = p4[j];
            #pragma unroll
            for (int i = 0; i < 4; ++i) {
                const int m = r0 + i*16;
                floatx4 v = half ? accB[i] : accA[i];
                const intx4 yv = y[j][i];
                #pragma unroll
                for (int rg = 0; rg < 4; ++rg) {
                    const int n = W + j*16 + (g << 2) + rg;
                    const float padn = (float)pm[rg];
                    float t = v[rg];
                    t = t * padn - (1.0f - padn) * BIGF;   // pad mask (ref order)
                    if (m > n) t -= BIGF;                  // tril(-1) causal mask
                    t *= 0.125f;                           // / sqrt(64)
                    v[rg] = t;
                    const int yy = yv[rg] & 1;
                    yb |= (unsigned)yy << cnt;
                    float vn = yy ? (-t - BIGF) : t;
                    float vp = yy ? (-t)        : (t - BIGF);
                    mxnj = fmaxf(mxnj, vn);
                    mxpj = fmaxf(mxpj, vp);
                    ++cnt;
                }
                if (half) accB[i] = v; else accA[i] = v;
            }
        }

        // --- aligned full-line stores (-1-shifted windows) ---
        #pragma unroll
        for (int i = 0; i < 4; ++i) {
            const floatx4 vA = accA[i], vB = accB[i];
            const int m = r0 + i*16;
            float* __restrict__ row = lgb + (m << 9);
            const float sameA  = __shfl(vA.w, (lane - 16) & 63);   // g-1's vA.w (g>0)
            const float tailA  = __shfl(tl[i], lr + 48);           // prev pair g3 tail
            const float sameB  = __shfl(vB.w, (lane - 16) & 63);   // g-1's vB.w (g>0)
            const float crossB = __shfl(vA.w, lr + 48);            // jA's g3 tail
            const float uA0 = (g == 0) ? tailA  : sameA;
            const float uB0 = (g == 0) ? crossB : sameB;
            if (jp == 0 && g == 0) {
                row[W] = vA.x;                                     // n=W       (4B, aligned)
                floatx2 h2 = { vA.y, vA.z };
                *(floatx2*)&row[W + 1] = h2;                       // n=W+1,2   (8B, aligned)
            } else {
                floatx4 uA = { uA0, vA.x, vA.y, vA.z };
                *(floatx4*)&row[W + jA*16 + (g << 2) - 1] = uA;    // 16B, aligned
            }
            floatx4 uB = { uB0, vB.x, vB.y, vB.z };
            *(floatx4*)&row[W + jB*16 + (g << 2) - 1] = uB;        // 16B, aligned
            tl[i] = vB.w;
        }

        // --- pass B: independent exps, merge into running LSE ---
        float smnj = 0.f, smpj = 0.f;
        cnt = 0;
        #pragma unroll
        for (int half = 0; half < 2; ++half) {
            #pragma unroll
            for (int i = 0; i < 4; ++i) {
                const floatx4 v = half ? accB[i] : accA[i];
                #pragma unroll
                for (int rg = 0; rg < 4; ++rg) {
                    const float t = v[rg];
                    const int yy = (int)((yb >> cnt) & 1u);
                    float vn = yy ? (-t - BIGF) : t;
                    float vp = yy ? (-t)        : (t - BIGF);
                    smnj += __expf(vn - mxnj);
                    smpj += __expf(vp - mxpj);
                    ++cnt;
                }
            }
        }
        lse_merge(mxn, smn, mxnj, smnj);
        lse_merge(mxp, smp, mxpj, smpj);
    }

    // final per-row tail stores: n = W+63 (4B, aligned), g==3 lanes hold it
    if (g == 3) {
        #pragma unroll
        for (int i = 0; i < 4; ++i) {
            const int m = r0 + i*16;
            lgb[(m << 9) + W + 63] = tl[i];
        }
    }

    // ---- wave reduce (64 lanes) ----
    #pragma unroll
    for (int off = 32; off > 0; off >>= 1) {
        float mo = __shfl_down(mxn, off), so = __shfl_down(smn, off);
        lse_merge(mxn, smn, mo, so);
        mo = __shfl_down(mxp, off); so = __shfl_down(smp, off);
        lse_merge(mxp, smp, mo, so);
    }
    if (lane == 0) { smx[0][wave] = mxn; ssm[0][wave] = smn; smx[1][wave] = mxp; ssm[1][wave] = smp; }
    __syncthreads();
    if (tid == 0) {
        float mn = smx[0][0], sn = ssm[0][0], mp = smx[1][0], sp = ssm[1][0];
        #pragma unroll
        for (int u = 1; u < 4; ++u) {
            lse_merge(mn, sn, smx[0][u], ssm[0][u]);
            lse_merge(mp, sp, smx[1][u], ssm[1][u]);
        }
        const int chunk = blockIdx.x * 4 + blockIdx.y;      // 0..15
        float4 res = {mn, sn, mp, sp};
        *(float4*)&partials[(size_t)(bh * NCHUNK + chunk) * 4] = res;
    }
}

static __device__ __forceinline__ float lae0(float x) {   // logaddexp(0, x)
    return fmaxf(x, 0.f) + log1pf(__expf(-fabsf(x)));
}

__global__ __launch_bounds__(256) void ce_final_kernel(
    const float* __restrict__ partials, float* __restrict__ out)
{
    __shared__ float red[256];
    const int t = threadIdx.x;
    float val = 0.f;
    if (t < BATCH * ENTS) {
        float mn = -3.0e38f, sn = 0.f, mp = -3.0e38f, sp = 0.f;
        for (int c = 0; c < NCHUNK; ++c) {
            const float* p = &partials[(size_t)(t * NCHUNK + c) * 4];
            lse_merge(mn, sn, p[0], p[1]);
            lse_merge(mp, sp, p[2], p[3]);
        }
        float lsen = mn + logf(sn);
        float lsep = mp + logf(sp);
        val = lae0(lsen) + lae0(lsep);
    }
    red[t] = val;
    __syncthreads();
    for (int s2 = 128; s2 > 0; s2 >>= 1) {
        if (t < s2) red[t] += red[t + s2];
        __syncthreads();
    }
    if (t == 0) out[0] = red[0] / (float)(BATCH * ENTS);
}

extern "C" void kernel_launch(void* const* d_in, const int* in_sizes, int n_in,
                              void* d_out, int out_size, void* d_ws, size_t ws_size,
                              hipStream_t stream) {
    const float* X      = (const float*)d_in[0];   // (16,512,768)
    const int*   amask  = (const int*)d_in[1];     // (16,512)
    const int*   labels = (const int*)d_in[2];     // (16,9,512,512)
    const float* W      = (const float*)d_in[3];   // (768,1152)
    const float* bias   = (const float*)d_in[4];   // (1152,)

    float* out    = (float*)d_out;
    float* logits = out + 1;                       // temp_logits (16,9,512,512)

    float* sin_t = (float*)d_ws;                         // 16384 f32
    float* cos_t = sin_t + SEQ * 32;                     // 16384 f32
    ushort_t* Xb   = (ushort_t*)(cos_t + SEQ * 32);      // 6291456 bf16
    ushort_t* Wt   = Xb + (size_t)BATCH * SEQ * HID;     // 884736 bf16  [n][k]
    ushort_t* qbuf = Wt + (size_t)NOUT * HID;            // 16*9*512*64 bf16
    ushort_t* kbuf = qbuf + (size_t)BATCH * ENTS * SEQ * DD;
    float* partials = (float*)(kbuf + (size_t)BATCH * ENTS * SEQ * DD); // 144*16*4 f32

    rope_table_kernel<<<64, 256, 0, stream>>>(sin_t, cos_t);
    cvt_x_kernel<<<1024, 256, 0, stream>>>(X, Xb, BATCH * SEQ * HID);
    cvt_w_kernel<<<(NOUT * HID + 255) / 256, 256, 0, stream>>>(W, Wt);
    proj_rope_kernel<<<dim3(64, 9), 256, 0, stream>>>(Xb, Wt, bias, sin_t, cos_t, qbuf, kbuf);
    qk_mask_ce_kernel<<<dim3(4, 4, 144), 256, 0, stream>>>(qbuf, kbuf, amask, labels, logits, partials);
    ce_final_kernel<<<1, 256, 0, stream>>>(partials, out);
}

// Round 8
// 154.615 us; speedup vs baseline: 1.0849x; 1.0849x over previous
//
#include <hip/hip_runtime.h>
#include <hip/hip_bf16.h>

#define HID 768
#define ENTS 9
#define DD 64
#define NOUT 1152     // ENTS*2*DD
#define BATCH 16
#define SEQ 512
#define BIGF 1000000000000.0f
#define BIG8 125000000000.0f   // BIGF * 0.125, fixed pos-side reference max
#define NCHUNK 16

typedef __attribute__((ext_vector_type(8))) short short8;
typedef __attribute__((ext_vector_type(4))) short short4_t;
typedef __attribute__((ext_vector_type(4))) float floatx4;
typedef __attribute__((ext_vector_type(2))) float floatx2;
typedef __attribute__((ext_vector_type(4))) int intx4;
typedef unsigned short ushort_t;

static __device__ __forceinline__ ushort_t f2bf(float x) {
    unsigned int u = __float_as_uint(x);
    unsigned int r = (u + 0x7FFFu + ((u >> 16) & 1u)) >> 16;   // RNE
    return (ushort_t)r;
}

static __device__ __forceinline__ void gload16(const void* g, void* l) {
    __builtin_amdgcn_global_load_lds(
        (const __attribute__((address_space(1))) void*)g,
        (__attribute__((address_space(3))) void*)l, 16, 0, 0);
}

// ---------------- RoPE tables: sin/cos (SEQ x 32) ----------------
__global__ void rope_table_kernel(float* __restrict__ sin_t, float* __restrict__ cos_t) {
    int idx = blockIdx.x * blockDim.x + threadIdx.x;   // 512*32 = 16384
    if (idx >= SEQ * 32) return;
    int m = idx >> 5, i = idx & 31;
    float inv = powf(10000.0f, -2.0f * (float)i / 64.0f);
    float ang = (float)m * inv;
    sin_t[idx] = sinf(ang);
    cos_t[idx] = cosf(ang);
}

// ---------------- f32 -> bf16 convert (X) ----------------
__global__ void cvt_x_kernel(const float* __restrict__ X, ushort_t* __restrict__ Xb, int n) {
    int i = (blockIdx.x * blockDim.x + threadIdx.x) * 4;
    int stride = gridDim.x * blockDim.x * 4;
    for (; i < n; i += stride) {
        float4 f = *(const float4*)&X[i];
        ushort_t u0 = f2bf(f.x), u1 = f2bf(f.y), u2 = f2bf(f.z), u3 = f2bf(f.w);
        ushort_t* p = &Xb[i];
        p[0] = u0; p[1] = u1; p[2] = u2; p[3] = u3;
    }
}

// ---------------- W transpose + convert: Wt[n][k] = bf16(W[k][n]) ----------------
__global__ void cvt_w_kernel(const float* __restrict__ W, ushort_t* __restrict__ Wt) {
    int idx = blockIdx.x * blockDim.x + threadIdx.x;   // over 1152*768
    if (idx >= NOUT * HID) return;
    int n = idx / HID, k = idx - n * HID;
    Wt[idx] = f2bf(W[(size_t)k * NOUT + n]);
}

// ---------------- Projection GEMM + bias + RoPE + pack to q/k bf16 ----------------
__global__ __launch_bounds__(256) void proj_rope_kernel(
    const ushort_t* __restrict__ Xb, const ushort_t* __restrict__ Wt,
    const float* __restrict__ bias,
    const float* __restrict__ sin_t, const float* __restrict__ cos_t,
    ushort_t* __restrict__ qbuf, ushort_t* __restrict__ kbuf)
{
    __shared__ ushort_t As[128 * 32];   // linear: global_load_lds dest
    __shared__ ushort_t Bs[128 * 32];
    const int tid  = threadIdx.x;
    const int lane = tid & 63;
    const int wave = tid >> 6;
    const int bm = blockIdx.x * 128;
    const int bn = blockIdx.y * 128;
    const int wm = (wave >> 1) * 64;
    const int wn = (wave & 1) * 64;

    floatx4 acc[4][4];
    #pragma unroll
    for (int j = 0; j < 4; ++j)
        #pragma unroll
        for (int i = 0; i < 4; ++i) { floatx4 z = {0.f,0.f,0.f,0.f}; acc[j][i] = z; }

    const int c0 = wave * 64 + lane;
    const int c1 = 256 + wave * 64 + lane;
    const int r0 = c0 >> 2, q0 = (c0 & 3) * 8;
    const int r1 = c1 >> 2, q1 = (c1 & 3) * 8;
    ushort_t* ldsA0 = As + wave * 512;
    ushort_t* ldsA1 = As + 2048 + wave * 512;
    ushort_t* ldsB0 = Bs + wave * 512;
    ushort_t* ldsB1 = Bs + 2048 + wave * 512;

    const int ko = (lane >> 4) * 8;
    const int lr = lane & 15;

    for (int kt = 0; kt < HID; kt += 32) {
        gload16(&Xb[(size_t)(bm + r0) * HID + kt + q0], ldsA0);
        gload16(&Xb[(size_t)(bm + r1) * HID + kt + q1], ldsA1);
        gload16(&Wt[(size_t)(bn + r0) * HID + kt + q0], ldsB0);
        gload16(&Wt[(size_t)(bn + r1) * HID + kt + q1], ldsB1);
        __syncthreads();

        short8 a[4], b[4];
        #pragma unroll
        for (int i = 0; i < 4; ++i) a[i] = *(const short8*)&As[(wm + i*16 + lr) * 32 + ko];
        #pragma unroll
        for (int j = 0; j < 4; ++j) b[j] = *(const short8*)&Bs[(wn + j*16 + lr) * 32 + ko];
        #pragma unroll
        for (int j = 0; j < 4; ++j)
            #pragma unroll
            for (int i = 0; i < 4; ++i)
                acc[j][i] = __builtin_amdgcn_mfma_f32_16x16x32_bf16(b[j], a[i], acc[j][i], 0, 0, 0);
        __syncthreads();
    }

    #pragma unroll
    for (int j = 0; j < 4; ++j) {
        const int n0 = bn + wn + j*16 + (lane >> 4) * 4;   // 4 consecutive n
        const int e   = n0 >> 7;
        const int dd0 = n0 & 127;
        const bool isq = dd0 < DD;
        const int d0  = isq ? dd0 : dd0 - DD;              // multiple of 4
        const float4 bv = *(const float4*)&bias[n0];
        #pragma unroll
        for (int i = 0; i < 4; ++i) {
            const int m = bm + wm + i*16 + lr;
            const int s  = m & (SEQ - 1);
            const int bb = m >> 9;
            const float c0f = cos_t[s*32 + (d0 >> 1)];
            const float s0f = sin_t[s*32 + (d0 >> 1)];
            const float c1f = cos_t[s*32 + (d0 >> 1) + 1];
            const float s1f = sin_t[s*32 + (d0 >> 1) + 1];
            const float v0 = acc[j][i][0] + bv.x;
            const float v1 = acc[j][i][1] + bv.y;
            const float v2 = acc[j][i][2] + bv.z;
            const float v3 = acc[j][i][3] + bv.w;
            const float o0 = v0 * c0f - v1 * s0f;
            const float o1 = v1 * c0f + v0 * s0f;
            const float o2 = v2 * c1f - v3 * s1f;
            const float o3 = v3 * c1f + v2 * s1f;
            short4_t sv = { (short)f2bf(o0), (short)f2bf(o1), (short)f2bf(o2), (short)f2bf(o3) };
            size_t oidx = (((size_t)(bb * ENTS + e) * SEQ) + s) * DD + d0;
            *(short4_t*)&(isq ? qbuf : kbuf)[oidx] = sv;
        }
    }
}

// ---------------- Batched QK^T + masks + scale -> temp_logits, FUSED CE partials ----------------
// R5 structure (LDS staging + entry-barrier drain of all prefetches), single-pass
// fixed-reference CE: M_n = 0, M_p = BIG8, computed with cancellation-free selects:
//   u  = (+-t) via sign-bit xor with label (exact)
//   vn = u + (y ? -BIGF : 0)          ; exp(vn):  y=0 unmasked e^t, else ~0
//   ap = u + (y ? -BIG8 : -BIGF)      ; exp(ap):  y=1 masked exp(0)=1 EXACT, else ~0
// (masked t rounds to exactly -BIG8 in f32 since ulp(1.25e11)=8192 >> |dot/8|)
__global__ __launch_bounds__(256) void qk_mask_ce_kernel(
    const ushort_t* __restrict__ qbuf, const ushort_t* __restrict__ kbuf,
    const int* __restrict__ amask, const int* __restrict__ labels,
    float* __restrict__ logits, float* __restrict__ partials)
{
    __shared__ ushort_t Qs[128][72];
    __shared__ ushort_t Ks[128][72];
    __shared__ float ssn[4], ssp[4];
    const int tid  = threadIdx.x;
    const int lane = tid & 63;
    const int wave = tid >> 6;
    const int bm = blockIdx.x * 128;
    const int bn = blockIdx.y * 128;
    const int bh = blockIdx.z;           // b*ENTS + h
    const int b  = bh / ENTS;
    const int wm = (wave >> 1) * 64;
    const int wn = (wave & 1) * 64;
    const size_t base = (size_t)bh * SEQ * DD;

    const int g  = lane >> 4;
    const int lr = lane & 15;
    const int ko = g * 8;
    const int r0 = bm + wm + lr;                 // m base (i=0)
    const int W  = bn + wn;                      // wave n-column base (64-wide)
    const int n00 = W + (g << 2);
    const int bhbase = bh << 18;                 // bh*512*512 (fits int)

    // tril case, uniform per block: lower (all m>n) folds into constants;
    // diagonal blocks do a per-element compare.
    const bool diag = (blockIdx.x == blockIdx.y);
    const float lowAdj = (blockIdx.x > blockIdx.y) ? -BIG8 : 0.0f;

    // ---- prefetch ALL labels for this thread's 64 outputs (nt) ----
    intx4 y[4][4];
    #pragma unroll
    for (int j = 0; j < 4; ++j)
        #pragma unroll
        for (int i = 0; i < 4; ++i)
            y[j][i] = __builtin_nontemporal_load(
                (const intx4*)&labels[bhbase + ((r0 + i*16) << 9) + n00 + j*16]);

    // per-j per-rg constants: pm8 = pad*0.125, pc = (pad-1)*BIG8 + lowAdj
    floatx4 pm8[4], pc[4];
    #pragma unroll
    for (int j = 0; j < 4; ++j) {
        const intx4 p4 = *(const intx4*)&amask[(b << 9) + n00 + j*16];
        #pragma unroll
        for (int rg = 0; rg < 4; ++rg) {
            const float pf = (float)p4[rg];
            pm8[j][rg] = pf * 0.125f;
            pc[j][rg]  = (pf - 1.0f) * BIG8 + lowAdj;
        }
    }

    // ---- stage q/k tiles to LDS (barrier drains label prefetch too) ----
    {
        const int r  = tid >> 1;
        const int ks = (tid & 1) * 32;
        const ushort_t* gq = &qbuf[base + (size_t)(bm + r) * DD + ks];
        const ushort_t* gk = &kbuf[base + (size_t)(bn + r) * DD + ks];
        #pragma unroll
        for (int u = 0; u < 4; ++u) {
            *(short8*)&Qs[r][ks + u*8] = *(const short8*)(gq + u*8);
            *(short8*)&Ks[r][ks + u*8] = *(const short8*)(gk + u*8);
        }
    }
    __syncthreads();

    // preload both K-step A-fragments (Q side)
    short8 a[2][4];
    #pragma unroll
    for (int kk = 0; kk < 2; ++kk)
        #pragma unroll
        for (int i = 0; i < 4; ++i)
            a[kk][i] = *(const short8*)&Qs[wm + i*16 + lr][kk*32 + ko];

    float smn = 0.f, smp = 0.f;
    float tl[4];                                  // per-row tail (valid on g==3 lanes)
    float* __restrict__ lgb = logits + bhbase;

    #pragma unroll
    for (int jp = 0; jp < 2; ++jp) {
        const int jA = jp * 2, jB = jp * 2 + 1;

        // --- MFMA for the pair ---
        floatx4 accA[4], accB[4];
        #pragma unroll
        for (int i = 0; i < 4; ++i) { floatx4 z = {0.f,0.f,0.f,0.f}; accA[i] = z; accB[i] = z; }
        #pragma unroll
        for (int kk = 0; kk < 2; ++kk) {
            const short8 bfA = *(const short8*)&Ks[wn + jA*16 + lr][kk*32 + ko];
            const short8 bfB = *(const short8*)&Ks[wn + jB*16 + lr][kk*32 + ko];
            #pragma unroll
            for (int i = 0; i < 4; ++i) {
                accA[i] = __builtin_amdgcn_mfma_f32_16x16x32_bf16(bfA, a[kk][i], accA[i], 0, 0, 0);
                accB[i] = __builtin_amdgcn_mfma_f32_16x16x32_bf16(bfB, a[kk][i], accB[i], 0, 0, 0);
            }
        }

        // --- single pass: mask + scale + CE sums (cancellation-free) ---
        #pragma unroll
        for (int half = 0; half < 2; ++half) {
            const int j = half ? jB : jA;
            const floatx4 pm = pm8[j], pcj = pc[j];
            const int n0j = W + j*16 + (g << 2);
            #pragma unroll
            for (int i = 0; i < 4; ++i) {
                const int m = r0 + i*16;
                const int d = m - n0j;                     // m>n0j+rg <=> d>rg
                floatx4 v = half ? accB[i] : accA[i];
                const intx4 yv = y[j][i];
                #pragma unroll
                for (int rg = 0; rg < 4; ++rg) {
                    float t = fmaf(v[rg], pm[rg], pcj[rg]);
                    if (diag && (d > rg)) t -= BIG8;       // tril on diagonal blocks
                    v[rg] = t;
                    const int yy = yv[rg] & 1;
                    // u = +-t exact via sign-bit xor
                    const float u = __uint_as_float(__float_as_uint(t) ^ ((unsigned)yy << 31));
                    const float cN = yy ? -BIGF : 0.0f;
                    const float cP = yy ? -BIG8 : -BIGF;
                    smn += __expf(u + cN);
                    smp += __expf(u + cP);
                }
                if (half) accB[i] = v; else accA[i] = v;
            }
        }

        // --- aligned full-line stores (-1-shifted windows) ---
        #pragma unroll
        for (int i = 0; i < 4; ++i) {
            const floatx4 vA = accA[i], vB = accB[i];
            const int m = r0 + i*16;
            float* __restrict__ row = lgb + (m << 9);
            const float sameA  = __shfl(vA.w, (lane - 16) & 63);   // g-1's vA.w (g>0)
            const float tailA  = __shfl(tl[i], lr + 48);           // prev pair g3 tail
            const float sameB  = __shfl(vB.w, (lane - 16) & 63);   // g-1's vB.w (g>0)
            const float crossB = __shfl(vA.w, lr + 48);            // jA's g3 tail
            const float uA0 = (g == 0) ? tailA  : sameA;
            const float uB0 = (g == 0) ? crossB : sameB;
            if (jp == 0 && g == 0) {
                row[W] = vA.x;                                     // n=W       (4B, aligned)
                floatx2 h2 = { vA.y, vA.z };
                *(floatx2*)&row[W + 1] = h2;                       // n=W+1,2   (8B, aligned)
            } else {
                floatx4 uA = { uA0, vA.x, vA.y, vA.z };
                *(floatx4*)&row[W + jA*16 + (g << 2) - 1] = uA;    // 16B, aligned
            }
            floatx4 uB = { uB0, vB.x, vB.y, vB.z };
            *(floatx4*)&row[W + jB*16 + (g << 2) - 1] = uB;        // 16B, aligned
            tl[i] = vB.w;
        }
    }

    // final per-row tail stores: n = W+63 (4B, aligned), g==3 lanes hold it
    if (g == 3) {
        #pragma unroll
        for (int i = 0; i < 4; ++i) {
            const int m = r0 + i*16;
            lgb[(m << 9) + W + 63] = tl[i];
        }
    }

    // ---- wave reduce: plain sums ----
    #pragma unroll
    for (int off = 32; off > 0; off >>= 1) {
        smn += __shfl_down(smn, off);
        smp += __shfl_down(smp, off);
    }
    if (lane == 0) { ssn[wave] = smn; ssp[wave] = smp; }
    __syncthreads();
    if (tid == 0) {
        float SN = ssn[0] + ssn[1] + ssn[2] + ssn[3];
        float SP = ssp[0] + ssp[1] + ssp[2] + ssp[3];
        const int chunk = blockIdx.x * 4 + blockIdx.y;      // 0..15
        floatx2 res = { SN, SP };
        *(floatx2*)&partials[(size_t)(bh * NCHUNK + chunk) * 2] = res;
    }
}

static __device__ __forceinline__ float lae0(float x) {   // logaddexp(0, x)
    return fmaxf(x, 0.f) + log1pf(__expf(-fabsf(x)));
}

__global__ __launch_bounds__(256) void ce_final_kernel(
    const float* __restrict__ partials, float* __restrict__ out)
{
    __shared__ float red[256];
    const int t = threadIdx.x;
    float val = 0.f;
    if (t < BATCH * ENTS) {
        float SN = 0.f, SP = 0.f;
        for (int c = 0; c < NCHUNK; ++c) {
            SN += partials[(size_t)(t * NCHUNK + c) * 2];
            SP += partials[(size_t)(t * NCHUNK + c) * 2 + 1];
        }
        const float neg = log1pf(SN);                 // logaddexp(0, log(SN))
        const float pos = lae0(BIG8 + logf(SP));      // M_p + log(SP); SP=0 -> 0
        val = neg + pos;
    }
    red[t] = val;
    __syncthreads();
    for (int s2 = 128; s2 > 0; s2 >>= 1) {
        if (t < s2) red[t] += red[t + s2];
        __syncthreads();
    }
    if (t == 0) out[0] = red[0] / (float)(BATCH * ENTS);
}

extern "C" void kernel_launch(void* const* d_in, const int* in_sizes, int n_in,
                              void* d_out, int out_size, void* d_ws, size_t ws_size,
                              hipStream_t stream) {
    const float* X      = (const float*)d_in[0];   // (16,512,768)
    const int*   amask  = (const int*)d_in[1];     // (16,512)
    const int*   labels = (const int*)d_in[2];     // (16,9,512,512)
    const float* W      = (const float*)d_in[3];   // (768,1152)
    const float* bias   = (const float*)d_in[4];   // (1152,)

    float* out    = (float*)d_out;
    float* logits = out + 1;                       // temp_logits (16,9,512,512)

    float* sin_t = (float*)d_ws;                         // 16384 f32
    float* cos_t = sin_t + SEQ * 32;                     // 16384 f32
    ushort_t* Xb   = (ushort_t*)(cos_t + SEQ * 32);      // 6291456 bf16
    ushort_t* Wt   = Xb + (size_t)BATCH * SEQ * HID;     // 884736 bf16  [n][k]
    ushort_t* qbuf = Wt + (size_t)NOUT * HID;            // 16*9*512*64 bf16
    ushort_t* kbuf = qbuf + (size_t)BATCH * ENTS * SEQ * DD;
    float* partials = (float*)(kbuf + (size_t)BATCH * ENTS * SEQ * DD); // 144*16*2 f32

    rope_table_kernel<<<64, 256, 0, stream>>>(sin_t, cos_t);
    cvt_x_kernel<<<1024, 256, 0, stream>>>(X, Xb, BATCH * SEQ * HID);
    cvt_w_kernel<<<(NOUT * HID + 255) / 256, 256, 0, stream>>>(W, Wt);
    proj_rope_kernel<<<dim3(64, 9), 256, 0, stream>>>(Xb, Wt, bias, sin_t, cos_t, qbuf, kbuf);
    qk_mask_ce_kernel<<<dim3(4, 4, 144), 256, 0, stream>>>(qbuf, kbuf, amask, labels, logits, partials);
    ce_final_kernel<<<1, 256, 0, stream>>>(partials, out);
}